// Round 5
// baseline (1142.828 us; speedup 1.0000x reference)
//
#include <hip/hip_runtime.h>
#include <hip/hip_bf16.h>
#include <math.h>

// ---------------------------------------------------------------------------
// VQ-VAE forward. B=64, CIN=3, H=W=256, K=512, D=4, f32.
// Round 5 = round 3 resubmit (rounds 3 and 4 never ran: GPU acquisition
// timeouts at the broker; kernel is still unmeasured).
// Parity-decomposed convT (uniform taps, col-pair threads), LDS-tiled conv1
// with 4-px register blocking, co-major weight LDS layout, quad dec3.
// ---------------------------------------------------------------------------

#define EPSV 1e-5f

// ---- fused per-block stats partial write (sum/sumsq per channel) -----------
template<int COUT, int NW>
__device__ __forceinline__ void stats_write(float (&s)[COUT], float (&q)[COUT],
    float* __restrict__ psum, float* __restrict__ psq, int bid, int NB,
    float* redbuf, int tid) {
    const int lane = tid & 63, wid = tid >> 6;
    #pragma unroll
    for (int co = 0; co < COUT; ++co) {
        float ss = s[co], qq = q[co];
        #pragma unroll
        for (int o = 32; o > 0; o >>= 1) {
            ss += __shfl_down(ss, o, 64);
            qq += __shfl_down(qq, o, 64);
        }
        if (lane == 0) {
            redbuf[wid * 2 * COUT + 2 * co]     = ss;
            redbuf[wid * 2 * COUT + 2 * co + 1] = qq;
        }
    }
    __syncthreads();
    if (tid < 2 * COUT) {
        float v = 0.f;
        #pragma unroll
        for (int w = 0; w < NW; ++w) v += redbuf[w * 2 * COUT + tid];
        if (tid & 1) psq [(tid >> 1) * NB + bid] = v;
        else         psum[(tid >> 1) * NB + bid] = v;
    }
}

// ---- stats finalize: per-channel scale/shift --------------------------------
template<int C>
__global__ __launch_bounds__(64)
void red_final_k(const float* __restrict__ psum, const float* __restrict__ psq,
                 const float* __restrict__ g, const float* __restrict__ b,
                 float* __restrict__ ss, float inv_count, int NB) {
    const int c = blockIdx.x;
    float s = 0.f, q = 0.f;
    for (int i = threadIdx.x; i < NB; i += 64) { s += psum[c * NB + i]; q += psq[c * NB + i]; }
    #pragma unroll
    for (int o = 32; o > 0; o >>= 1) {
        s += __shfl_down(s, o, 64);
        q += __shfl_down(q, o, 64);
    }
    if (threadIdx.x == 0) {
        const float mean = s * inv_count;
        const float var  = q * inv_count - mean * mean;
        const float rstd = 1.f / sqrtf(var + EPSV);
        const float sc   = g[c] * rstd;
        ss[2 * c]     = sc;
        ss[2 * c + 1] = b[c] - mean * sc;
    }
}

// ---- encoder conv1: 3->8, 5x5 s2 p1, 256->127. LDS tile, PX=4. -------------
// block 128 = 4 ty x 32 tx; covers 4 output rows x full width (ox = tx+32p).
__global__ __launch_bounds__(128)
void conv1_k(const float* __restrict__ in, const float* __restrict__ w,
             float* __restrict__ out, float* __restrict__ psum,
             float* __restrict__ psq) {
    __shared__ float tile[3 * 11 * 264];     // rows: 8*by-1 .. +10; cols -1..255 (+pad)
    __shared__ float wl[600];                // [ci][kh][kw][co]
    __shared__ float redbuf[2 * 2 * 8];
    const int tid = threadIdx.x;
    const int by = blockIdx.y, n = blockIdx.z;

    for (int i = tid; i < 600; i += 128) {   // transpose OIHW -> tap-major,co-minor
        const int co = i & 7, rest = i >> 3; // rest = (ci*5+kh)*5+kw
        wl[i] = w[co * 75 + rest];
    }
    const int iy_org = 8 * by - 1;
    const float* inb = in + (size_t)n * 3 * 256 * 256;
    for (int i = tid; i < 3 * 11 * 264; i += 128) {
        const int c = i % 264, rc = i / 264, r = rc % 11, ci = rc / 11;
        const int gy = iy_org + r, gx = c - 1;
        float v = 0.f;
        if (c < 258 && (unsigned)gy < 256u && (unsigned)gx < 256u)
            v = inb[(ci * 256 + gy) * 256 + gx];
        tile[(ci * 11 + r) * 264 + c] = v;
    }
    __syncthreads();

    const int ty = tid >> 5, tx = tid & 31;
    const int oy = 4 * by + ty;
    float acc[4][8];
    #pragma unroll
    for (int p = 0; p < 4; ++p)
        #pragma unroll
        for (int co = 0; co < 8; ++co) acc[p][co] = 0.f;

    #pragma unroll
    for (int ci = 0; ci < 3; ++ci) {
        #pragma unroll
        for (int kh = 0; kh < 5; ++kh) {
            const float* trow = &tile[(ci * 11 + 2 * ty + kh) * 264];
            #pragma unroll
            for (int kw = 0; kw < 5; ++kw) {
                float wv[8];
                #pragma unroll
                for (int co = 0; co < 8; ++co)
                    wv[co] = wl[((ci * 5 + kh) * 5 + kw) * 8 + co];
                #pragma unroll
                for (int p = 0; p < 4; ++p) {
                    const float v = trow[2 * (tx + 32 * p) + kw];
                    #pragma unroll
                    for (int co = 0; co < 8; ++co) acc[p][co] = fmaf(v, wv[co], acc[p][co]);
                }
            }
        }
    }
    // zero invalid pixels (for clean stats)
    if (oy >= 127) {
        #pragma unroll
        for (int p = 0; p < 4; ++p)
            #pragma unroll
            for (int co = 0; co < 8; ++co) acc[p][co] = 0.f;
    }
    #pragma unroll
    for (int p = 0; p < 4; ++p)
        if (tx + 32 * p >= 127) {
            #pragma unroll
            for (int co = 0; co < 8; ++co) acc[p][co] = 0.f;
        }
    if (oy < 127) {
        #pragma unroll
        for (int p = 0; p < 4; ++p) {
            const int ox = tx + 32 * p;
            if (ox < 127) {
                #pragma unroll
                for (int co = 0; co < 8; ++co)
                    out[(((size_t)n * 8 + co) * 127 + oy) * 127 + ox] = acc[p][co];
            }
        }
    }
    float s[8], q[8];
    #pragma unroll
    for (int co = 0; co < 8; ++co) {
        s[co] = acc[0][co] + acc[1][co] + acc[2][co] + acc[3][co];
        q[co] = acc[0][co] * acc[0][co] + acc[1][co] * acc[1][co]
              + acc[2][co] * acc[2][co] + acc[3][co] * acc[3][co];
    }
    stats_write<8, 2>(s, q, psum, psq, n * 32 + by, 2048, redbuf, tid);
}

// ---- encoder conv2: 8->16, 3x3 s2 p1, 127->64. direct global, PX=2. --------
// block 256 = 8 ty x 32 tx; ox = tx + 32p. BN1+ReLU fused on load.
__global__ __launch_bounds__(256)
void conv2_k(const float* __restrict__ in, const float* __restrict__ w,
             const float* __restrict__ ssin, float* __restrict__ out,
             float* __restrict__ psum, float* __restrict__ psq) {
    __shared__ float wl[8 * 9 * 16];         // [ci*9+k][co]
    __shared__ float ssl[16];
    __shared__ float redbuf[4 * 2 * 16];
    const int tid = threadIdx.x;
    const int by = blockIdx.y, n = blockIdx.z;
    for (int i = tid; i < 1152; i += 256) {
        const int co = i & 15, rest = i >> 4; // rest = ci*9+k
        wl[i] = w[co * 72 + rest];
    }
    if (tid < 16) ssl[tid] = ssin[tid];
    __syncthreads();

    const int ty = tid >> 5, tx = tid & 31;
    const int oy = 8 * by + ty;              // 0..63, always valid
    const float* inb = in + (size_t)n * 8 * 127 * 127;
    float acc[2][16];
    #pragma unroll
    for (int p = 0; p < 2; ++p)
        #pragma unroll
        for (int co = 0; co < 16; ++co) acc[p][co] = 0.f;

    #pragma unroll
    for (int ci = 0; ci < 8; ++ci) {
        const float sc = ssl[2 * ci], sh = ssl[2 * ci + 1];
        #pragma unroll
        for (int kh = 0; kh < 3; ++kh) {
            const int iy = 2 * oy - 1 + kh;
            const bool vy = (unsigned)iy < 127u;
            #pragma unroll
            for (int kw = 0; kw < 3; ++kw) {
                float wv[16];
                #pragma unroll
                for (int co = 0; co < 16; ++co)
                    wv[co] = wl[(ci * 9 + kh * 3 + kw) * 16 + co];
                #pragma unroll
                for (int p = 0; p < 2; ++p) {
                    const int ox = tx + 32 * p;
                    const int ix = 2 * ox - 1 + kw;
                    float v = 0.f;
                    if (vy && (unsigned)ix < 127u)
                        v = fmaxf(inb[(ci * 127 + iy) * 127 + ix] * sc + sh, 0.f);
                    #pragma unroll
                    for (int co = 0; co < 16; ++co) acc[p][co] = fmaf(v, wv[co], acc[p][co]);
                }
            }
        }
    }
    #pragma unroll
    for (int p = 0; p < 2; ++p) {
        const int ox = tx + 32 * p;
        #pragma unroll
        for (int co = 0; co < 16; ++co)
            out[(((size_t)n * 16 + co) * 64 + oy) * 64 + ox] = acc[p][co];
    }
    float s[16], q[16];
    #pragma unroll
    for (int co = 0; co < 16; ++co) {
        s[co] = acc[0][co] + acc[1][co];
        q[co] = acc[0][co] * acc[0][co] + acc[1][co] * acc[1][co];
    }
    stats_write<16, 4>(s, q, psum, psq, n * 8 + by, 512, redbuf, tid);
}

// ---- encoder conv3: 16->4, 3x3 s2 p1, 64->32. BN2+ReLU fused on load. ------
__global__ __launch_bounds__(256)
void conv3_k(const float* __restrict__ in, const float* __restrict__ w,
             const float* __restrict__ ssin, float* __restrict__ out,
             float* __restrict__ psum, float* __restrict__ psq) {
    __shared__ float wl[16 * 9 * 4];         // [ci*9+k][co]
    __shared__ float ssl[32];
    __shared__ float redbuf[4 * 2 * 4];
    const int tid = threadIdx.x;
    const int bx = blockIdx.x, n = blockIdx.z;
    for (int i = tid; i < 576; i += 256) {
        const int co = i & 3, rest = i >> 2;
        wl[i] = w[co * 144 + rest];
    }
    if (tid < 32) ssl[tid] = ssin[tid];
    __syncthreads();

    const int p = bx * 256 + tid;            // 0..1023 exact
    const int oy = p >> 5, ox = p & 31;
    const float* inb = in + (size_t)n * 16 * 64 * 64;
    float acc[4] = {0.f, 0.f, 0.f, 0.f};
    #pragma unroll
    for (int ci = 0; ci < 16; ++ci) {
        const float sc = ssl[2 * ci], sh = ssl[2 * ci + 1];
        #pragma unroll
        for (int kh = 0; kh < 3; ++kh) {
            const int iy = 2 * oy - 1 + kh;
            const bool vy = (unsigned)iy < 64u;
            #pragma unroll
            for (int kw = 0; kw < 3; ++kw) {
                const int ix = 2 * ox - 1 + kw;
                float v = 0.f;
                if (vy && (unsigned)ix < 64u)
                    v = fmaxf(inb[(ci * 64 + iy) * 64 + ix] * sc + sh, 0.f);
                #pragma unroll
                for (int co = 0; co < 4; ++co)
                    acc[co] = fmaf(v, wl[(ci * 9 + kh * 3 + kw) * 4 + co], acc[co]);
            }
        }
    }
    #pragma unroll
    for (int co = 0; co < 4; ++co)
        out[((size_t)n * 4 + co) * 1024 + p] = acc[co];
    float s[4], q[4];
    #pragma unroll
    for (int co = 0; co < 4; ++co) { s[co] = acc[co]; q[co] = acc[co] * acc[co]; }
    stats_write<4, 4>(s, q, psum, psq, n * 4 + bx, 256, redbuf, tid);
}

// ---- VQ with fused BN3+ReLU of latents -------------------------------------
__global__ __launch_bounds__(256)
void vq_k(const float* __restrict__ raw, const float* __restrict__ ss,
          const float* __restrict__ emb, float* __restrict__ out_lat,
          float* __restrict__ out_q, float* __restrict__ lossp) {
    __shared__ float e[512 * 4];
    __shared__ float ee[512];
    __shared__ float ssl[8];
    __shared__ float redbuf[4];
    for (int i = threadIdx.x; i < 512 * 4; i += 256) e[i] = emb[i];
    if (threadIdx.x < 8) ssl[threadIdx.x] = ss[threadIdx.x];
    __syncthreads();
    for (int k = threadIdx.x; k < 512; k += 256) {
        float s = 0.f;
        #pragma unroll
        for (int d = 0; d < 4; ++d) { const float v = e[k * 4 + d]; s += v * v; }
        ee[k] = s;
    }
    __syncthreads();

    const int t = blockIdx.x * 256 + threadIdx.x;
    const int b = t >> 10, p = t & 1023;
    const float* rb = raw + ((size_t)b * 4) * 1024 + p;
    const float z0 = fmaxf(rb[0]    * ssl[0] + ssl[1], 0.f);
    const float z1 = fmaxf(rb[1024] * ssl[2] + ssl[3], 0.f);
    const float z2 = fmaxf(rb[2048] * ssl[4] + ssl[5], 0.f);
    const float z3 = fmaxf(rb[3072] * ssl[6] + ssl[7], 0.f);
    float* lb = out_lat + ((size_t)b * 4) * 1024 + p;
    lb[0] = z0; lb[1024] = z1; lb[2048] = z2; lb[3072] = z3;

    const float zz = z0 * z0 + z1 * z1 + z2 * z2 + z3 * z3;
    int best = 0;
    float bd = INFINITY;
    #pragma unroll 8
    for (int k = 0; k < 512; ++k) {
        const float dot = z0 * e[k * 4] + z1 * e[k * 4 + 1] + z2 * e[k * 4 + 2] + z3 * e[k * 4 + 3];
        const float d = zz - 2.f * dot + ee[k];   // expanded form, as reference
        if (d < bd) { bd = d; best = k; }         // strict < = first-occurrence argmin
    }
    const float q0 = e[best * 4], q1 = e[best * 4 + 1], q2 = e[best * 4 + 2], q3 = e[best * 4 + 3];
    float* qb = out_q + ((size_t)b * 4) * 1024 + p;
    qb[0] = q0; qb[1024] = q1; qb[2048] = q2; qb[3072] = q3;

    float ssd = (q0 - z0) * (q0 - z0) + (q1 - z1) * (q1 - z1)
              + (q2 - z2) * (q2 - z2) + (q3 - z3) * (q3 - z3);
    #pragma unroll
    for (int o = 32; o > 0; o >>= 1) ssd += __shfl_down(ssd, o, 64);
    const int lane = threadIdx.x & 63, wid = threadIdx.x >> 6;
    if (lane == 0) redbuf[wid] = ssd;
    __syncthreads();
    if (threadIdx.x == 0)
        lossp[blockIdx.x] = redbuf[0] + redbuf[1] + redbuf[2] + redbuf[3];
}

__global__ __launch_bounds__(256)
void loss_final_k(const float* __restrict__ partial, float* __restrict__ out_cb,
                  float* __restrict__ out_cm) {
    __shared__ float redbuf[4];
    float s = partial[threadIdx.x];
    #pragma unroll
    for (int o = 32; o > 0; o >>= 1) s += __shfl_down(s, o, 64);
    const int lane = threadIdx.x & 63, wid = threadIdx.x >> 6;
    if (lane == 0) redbuf[wid] = s;
    __syncthreads();
    if (threadIdx.x == 0) {
        const float L = (redbuf[0] + redbuf[1] + redbuf[2] + redbuf[3]) * (1.f / 262144.f);
        *out_cb = L;
        *out_cm = L;
    }
}

// ---- decoder convT1: 4->16, 3x3 s2 p0, 32->65. Parity classes, col pairs. --
// blockIdx.y = row parity cy. Thread = (row ry, col-pair rx). Zero-masked loads
// implement tap-validity exactly (invalid tap contributes 0).
__global__ __launch_bounds__(256)
void dect1_k(const float* __restrict__ in, const float* __restrict__ w,
             float* __restrict__ out, float* __restrict__ psum,
             float* __restrict__ psq) {
    __shared__ float wl[4 * 9 * 16];         // [ci*9+k][co]
    __shared__ float redbuf[4 * 2 * 16];
    const int tid = threadIdx.x;
    const int cy = blockIdx.y, n = blockIdx.z;
    for (int i = tid; i < 576; i += 256) {
        const int co = i & 15, rest = i >> 4;        // rest = ci*9+k
        const int ci = rest / 9, k = rest % 9;
        wl[i] = w[(ci * 16 + co) * 9 + k];
    }
    __syncthreads();

    const int Ry = 33 - cy;                  // rows in this parity class
    const int p = blockIdx.x * 256 + tid;
    const bool active = p < Ry * 33;
    const int ry = p / 33, rx = p % 33;
    const int oy = 2 * ry + cy;
    float acc_e[16], acc_o[16];
    #pragma unroll
    for (int co = 0; co < 16; ++co) { acc_e[co] = 0.f; acc_o[co] = 0.f; }

    if (active) {
        const float* inb = in + (size_t)n * 4 * 1024;
        auto tap = [&](int kh, int iy, bool vy) {
            #pragma unroll
            for (int ci = 0; ci < 4; ++ci) {
                const float* r = inb + (ci * 32 + iy) * 32;
                const float vL = (vy && rx >= 1) ? r[rx - 1] : 0.f;   // kw=2 src
                const float vR = (vy && rx < 32) ? r[rx]     : 0.f;   // kw=0/1 src
                const float* wp = &wl[(ci * 9 + kh * 3) * 16];
                #pragma unroll
                for (int co = 0; co < 16; ++co) {
                    acc_e[co] = fmaf(vR, wp[co], fmaf(vL, wp[32 + co], acc_e[co]));
                    acc_o[co] = fmaf(vR, wp[16 + co], acc_o[co]);
                }
            }
        };
        if (cy == 0) { tap(0, ry, ry < 32); tap(2, ry - 1, ry >= 1); }
        else         { tap(1, ry, true); }

        #pragma unroll
        for (int co = 0; co < 16; ++co) {
            float* o = out + (((size_t)n * 16 + co) * 65 + oy) * 65 + 2 * rx;
            o[0] = acc_e[co];
            if (rx < 32) o[1] = acc_o[co];
        }
    }
    float s[16], q[16];
    #pragma unroll
    for (int co = 0; co < 16; ++co) {        // acc_o auto-0 at rx==32 (vR masked)
        s[co] = acc_e[co] + acc_o[co];
        q[co] = acc_e[co] * acc_e[co] + acc_o[co] * acc_o[co];
    }
    stats_write<16, 4>(s, q, psum, psq, (n * 2 + cy) * 5 + blockIdx.x, 640, redbuf, tid);
}

// ---- decoder convT2: 16->8, 3x3 s2 p1, 65->129. All taps valid (no checks).
// BN(dec1)+ReLU fused on load.
__global__ __launch_bounds__(256)
void dect2_k(const float* __restrict__ in, const float* __restrict__ w,
             const float* __restrict__ ssin, float* __restrict__ out,
             float* __restrict__ psum, float* __restrict__ psq) {
    __shared__ float wl[16 * 9 * 8];         // [ci*9+k][co]
    __shared__ float ssl[32];
    __shared__ float redbuf[4 * 2 * 8];
    const int tid = threadIdx.x;
    const int cy = blockIdx.y, n = blockIdx.z;
    for (int i = tid; i < 1152; i += 256) {
        const int co = i & 7, rest = i >> 3;
        const int ci = rest / 9, k = rest % 9;
        wl[i] = w[(ci * 8 + co) * 9 + k];
    }
    if (tid < 32) ssl[tid] = ssin[tid];
    __syncthreads();

    const int Ry = 65 - cy;
    const int p = blockIdx.x * 256 + tid;
    const bool active = p < Ry * 65;
    const int ry = p / 65, rx = p % 65;
    const int oy = 2 * ry + cy;
    float acc_e[8], acc_o[8];
    #pragma unroll
    for (int co = 0; co < 8; ++co) { acc_e[co] = 0.f; acc_o[co] = 0.f; }

    if (active) {
        const float* inb = in + (size_t)n * 16 * 65 * 65;
        auto tap = [&](int kh, int iy) {
            #pragma unroll
            for (int ci = 0; ci < 16; ++ci) {
                const float sc = ssl[2 * ci], sh = ssl[2 * ci + 1];
                const float* r = inb + (ci * 65 + iy) * 65;
                const float vR = fmaxf(r[rx] * sc + sh, 0.f);
                float vP = 0.f;
                if (rx < 64) vP = fmaxf(r[rx + 1] * sc + sh, 0.f);
                const float* wp = &wl[(ci * 9 + kh * 3) * 8];
                #pragma unroll
                for (int co = 0; co < 8; ++co) {
                    acc_e[co] = fmaf(vR, wp[8 + co], acc_e[co]);                       // kw=1
                    acc_o[co] = fmaf(vP, wp[co], fmaf(vR, wp[16 + co], acc_o[co]));    // kw=0,2
                }
            }
        };
        if (cy == 0) { tap(1, ry); }
        else         { tap(0, ry + 1); tap(2, ry); }

        if (rx >= 64) {                      // odd col 129 doesn't exist
            #pragma unroll
            for (int co = 0; co < 8; ++co) acc_o[co] = 0.f;
        }
        #pragma unroll
        for (int co = 0; co < 8; ++co) {
            float* o = out + (((size_t)n * 8 + co) * 129 + oy) * 129 + 2 * rx;
            o[0] = acc_e[co];
            if (rx < 64) o[1] = acc_o[co];
        }
    }
    float s[8], q[8];
    #pragma unroll
    for (int co = 0; co < 8; ++co) {
        s[co] = acc_e[co] + acc_o[co];
        q[co] = acc_e[co] * acc_e[co] + acc_o[co] * acc_o[co];
    }
    stats_write<8, 4>(s, q, psum, psq, (n * 2 + cy) * 17 + blockIdx.x, 2176, redbuf, tid);
}

// ---- decoder convT3: 8->3, 2x2 s2 p1, 129->256. 2x2 quad per thread. -------
// Exactly one tap per output; quad needs the 2x2 input patch, all in-bounds.
__global__ __launch_bounds__(256)
void dec3_k(const float* __restrict__ in, const float* __restrict__ w,
            const float* __restrict__ ssin, const float* __restrict__ bias,
            float* __restrict__ out) {
    __shared__ float wl[96];                 // (ci*3+co)*4 + kh*2+kw
    __shared__ float ssl[16];
    __shared__ float bl[3];
    const int tid = threadIdx.x;
    if (tid < 96) wl[tid] = w[tid];
    if (tid < 16) ssl[tid] = ssin[tid];
    if (tid < 3)  bl[tid] = bias[tid];
    __syncthreads();

    const int n = blockIdx.z;
    const int p = blockIdx.x * 256 + tid;    // 0..16383 exact (128x128 quads)
    const int ry = p >> 7, rx = p & 127;
    const float* inb = in + (size_t)n * 8 * 129 * 129;

    float acc[2][2][3];
    #pragma unroll
    for (int dy = 0; dy < 2; ++dy)
        #pragma unroll
        for (int dx = 0; dx < 2; ++dx)
            #pragma unroll
            for (int co = 0; co < 3; ++co) acc[dy][dx][co] = bl[co];

    #pragma unroll
    for (int ci = 0; ci < 8; ++ci) {
        const float sc = ssl[2 * ci], sh = ssl[2 * ci + 1];
        const float* base = inb + (ci * 129 + ry) * 129 + rx;
        const float v00 = fmaxf(base[0]   * sc + sh, 0.f);
        const float v01 = fmaxf(base[1]   * sc + sh, 0.f);
        const float v10 = fmaxf(base[129] * sc + sh, 0.f);
        const float v11 = fmaxf(base[130] * sc + sh, 0.f);
        #pragma unroll
        for (int co = 0; co < 3; ++co) {
            const int b = (ci * 3 + co) * 4;
            acc[0][0][co] = fmaf(v00, wl[b + 3], acc[0][0][co]);   // kh=1,kw=1
            acc[0][1][co] = fmaf(v01, wl[b + 2], acc[0][1][co]);   // kh=1,kw=0
            acc[1][0][co] = fmaf(v10, wl[b + 1], acc[1][0][co]);   // kh=0,kw=1
            acc[1][1][co] = fmaf(v11, wl[b + 0], acc[1][1][co]);   // kh=0,kw=0
        }
    }
    #pragma unroll
    for (int co = 0; co < 3; ++co) {
        #pragma unroll
        for (int dy = 0; dy < 2; ++dy) {
            float a0 = 1.f / (1.f + __expf(-acc[dy][0][co]));
            float a1 = 1.f / (1.f + __expf(-acc[dy][1][co]));
            float2 v2 = make_float2(a0, a1);
            float* o = out + (((size_t)n * 3 + co) << 16) + (size_t)(2 * ry + dy) * 256 + 2 * rx;
            *reinterpret_cast<float2*>(o) = v2;   // offset even -> 8B aligned
        }
    }
}

// ---------------------------------------------------------------------------
extern "C" void kernel_launch(void* const* d_in, const int* in_sizes, int n_in,
                              void* d_out, int out_size, void* d_ws, size_t ws_size,
                              hipStream_t stream) {
    const float* x      = (const float*)d_in[0];
    const float* ew1    = (const float*)d_in[1];
    const float* eg1    = (const float*)d_in[2];
    const float* eb1    = (const float*)d_in[3];
    const float* ew2    = (const float*)d_in[4];
    const float* eg2    = (const float*)d_in[5];
    const float* eb2    = (const float*)d_in[6];
    const float* ew3    = (const float*)d_in[7];
    const float* eg3    = (const float*)d_in[8];
    const float* eb3    = (const float*)d_in[9];
    const float* emb    = (const float*)d_in[10];
    const float* dw1    = (const float*)d_in[11];
    const float* dg1    = (const float*)d_in[12];
    const float* db1    = (const float*)d_in[13];
    const float* dw2    = (const float*)d_in[14];
    const float* dg2    = (const float*)d_in[15];
    const float* db2    = (const float*)d_in[16];
    const float* dw3    = (const float*)d_in[17];
    const float* dbias3 = (const float*)d_in[18];

    float* out_lat = (float*)d_out;
    float* out_q   = out_lat + 262144;
    float* out_dec = out_q + 262144;
    float* out_cb  = (float*)d_out + 13107200;
    float* out_cm  = out_cb + 1;

    float* bufA  = (float*)d_ws;          // h1 raw (8258048) then g2 raw (8520768)
    float* bufB  = bufA + 8520768;        // h2 raw (4194304) then g1 raw (4326400)
    float* bufC  = bufB + 4326400;        // conv3 raw, 262144
    float* psum  = bufC + 262144;
    float* psq   = psum + 18432;
    float* ssb   = psq + 18432;
    float* lossp = ssb + 32;

    // encoder 1: LDS-tiled, stats fused
    conv1_k<<<dim3(1, 32, 64), 128, 0, stream>>>(x, ew1, bufA, psum, psq);
    red_final_k<8><<<8, 64, 0, stream>>>(psum, psq, eg1, eb1, ssb,
                                         1.f / (64.f * 16129.f), 2048);
    // encoder 2: BN1+ReLU fused on load
    conv2_k<<<dim3(1, 8, 64), 256, 0, stream>>>(bufA, ew2, ssb, bufB, psum, psq);
    red_final_k<16><<<16, 64, 0, stream>>>(psum, psq, eg2, eb2, ssb,
                                           1.f / (64.f * 4096.f), 512);
    // encoder 3: BN2+ReLU fused on load
    conv3_k<<<dim3(4, 1, 64), 256, 0, stream>>>(bufB, ew3, ssb, bufC, psum, psq);
    red_final_k<4><<<4, 64, 0, stream>>>(psum, psq, eg3, eb3, ssb,
                                         1.f / (64.f * 1024.f), 256);
    // VQ (+ BN3+ReLU fused, latents written here) + losses
    vq_k<<<256, 256, 0, stream>>>(bufC, ssb, emb, out_lat, out_q, lossp);
    loss_final_k<<<1, 256, 0, stream>>>(lossp, out_cb, out_cm);
    // decoder 1: parity convT
    dect1_k<<<dim3(5, 2, 64), 256, 0, stream>>>(out_q, dw1, bufB, psum, psq);
    red_final_k<16><<<16, 64, 0, stream>>>(psum, psq, dg1, db1, ssb,
                                           1.f / (64.f * 4225.f), 640);
    // decoder 2: parity convT, BN(dec1)+ReLU fused
    dect2_k<<<dim3(17, 2, 64), 256, 0, stream>>>(bufB, dw2, ssb, bufA, psum, psq);
    red_final_k<8><<<8, 64, 0, stream>>>(psum, psq, dg2, db2, ssb,
                                         1.f / (64.f * 16641.f), 2176);
    // decoder 3: quad, BN(dec2)+ReLU fused, bias+sigmoid
    dec3_k<<<dim3(64, 1, 64), 256, 0, stream>>>(bufA, dw3, ssb, dbias3, out_dec);
}

// Round 11
// 457.327 us; speedup vs baseline: 2.4989x; 2.4989x over previous
//
#include <hip/hip_runtime.h>
#include <hip/hip_bf16.h>
#include <math.h>

// ---------------------------------------------------------------------------
// VQ-VAE forward. B=64, CIN=3, H=W=256, K=512, D=4, f32.
// Round 11 = round 6 resubmit (rounds 6-10 never ran: GPU acquisition
// timeouts at the broker; this change-set is still unmeasured).
// Register-disciplined rewrite of the validated round-3 math mappings:
// __launch_bounds__(256,4) VGPR cap, #pragma unroll 1 on ci/kh loops,
// float4 co-major LDS weight reads consumed immediately, acc <= 32 floats,
// no LDS input tiles. Fixes round-5's conv2 spill (VGPR 256, occ 9%,
// 676 MB scratch traffic, 387 us/dispatch).
// ---------------------------------------------------------------------------

#define EPSV 1e-5f

// ---- fused per-block stats partial write (sum/sumsq per channel) -----------
template<int COUT, int NW>
__device__ __forceinline__ void stats_write(float (&s)[COUT], float (&q)[COUT],
    float* __restrict__ psum, float* __restrict__ psq, int bid, int NB,
    float* redbuf, int tid) {
    const int lane = tid & 63, wid = tid >> 6;
    #pragma unroll
    for (int co = 0; co < COUT; ++co) {
        float ss = s[co], qq = q[co];
        #pragma unroll
        for (int o = 32; o > 0; o >>= 1) {
            ss += __shfl_down(ss, o, 64);
            qq += __shfl_down(qq, o, 64);
        }
        if (lane == 0) {
            redbuf[wid * 2 * COUT + 2 * co]     = ss;
            redbuf[wid * 2 * COUT + 2 * co + 1] = qq;
        }
    }
    __syncthreads();
    if (tid < 2 * COUT) {
        float v = 0.f;
        #pragma unroll
        for (int w = 0; w < NW; ++w) v += redbuf[w * 2 * COUT + tid];
        if (tid & 1) psq [(tid >> 1) * NB + bid] = v;
        else         psum[(tid >> 1) * NB + bid] = v;
    }
}

// ---- stats finalize: per-channel scale/shift --------------------------------
template<int C>
__global__ __launch_bounds__(64)
void red_final_k(const float* __restrict__ psum, const float* __restrict__ psq,
                 const float* __restrict__ g, const float* __restrict__ b,
                 float* __restrict__ ss, float inv_count, int NB) {
    const int c = blockIdx.x;
    float s = 0.f, q = 0.f;
    for (int i = threadIdx.x; i < NB; i += 64) { s += psum[c * NB + i]; q += psq[c * NB + i]; }
    #pragma unroll
    for (int o = 32; o > 0; o >>= 1) {
        s += __shfl_down(s, o, 64);
        q += __shfl_down(q, o, 64);
    }
    if (threadIdx.x == 0) {
        const float mean = s * inv_count;
        const float var  = q * inv_count - mean * mean;
        const float rstd = 1.f / sqrtf(var + EPSV);
        const float sc   = g[c] * rstd;
        ss[2 * c]     = sc;
        ss[2 * c + 1] = b[c] - mean * sc;
    }
}

// ---- encoder conv1: 3->8, 5x5 s2 p1, 256->127. Direct global, PX=4. --------
// block 256 = 8 ty x 32 tx; ox = tx+32p. grid (16,1,64) -> 4 waves/SIMD.
__global__ __launch_bounds__(256, 4)
void conv1_k(const float* __restrict__ in, const float* __restrict__ w,
             float* __restrict__ out, float* __restrict__ psum,
             float* __restrict__ psq) {
    __shared__ float wl[600];                // [tap][8co], tap=(ci*5+kh)*5+kw
    __shared__ float redbuf[4 * 2 * 8];
    const int tid = threadIdx.x;
    const int bx = blockIdx.x, n = blockIdx.z;
    for (int i = tid; i < 600; i += 256) {
        const int co = i & 7, tap = i >> 3;
        wl[i] = w[co * 75 + tap];
    }
    __syncthreads();

    const int ty = tid >> 5, tx = tid & 31;
    const int oy = bx * 8 + ty;              // 0..127 (127 invalid)
    const int iy0 = 2 * oy - 1;
    const float* inb = in + (size_t)n * 3 * 256 * 256;

    float acc[4][8];
    #pragma unroll
    for (int p = 0; p < 4; ++p)
        #pragma unroll
        for (int co = 0; co < 8; ++co) acc[p][co] = 0.f;

    #pragma unroll 1
    for (int ci = 0; ci < 3; ++ci) {
        #pragma unroll 1
        for (int kh = 0; kh < 5; ++kh) {
            const int iy = iy0 + kh;
            const bool vy = (unsigned)iy < 256u;
            const float* row = inb + (ci * 256 + iy) * 256;
            #pragma unroll
            for (int kw = 0; kw < 5; ++kw) {
                float v0 = 0.f, v1 = 0.f, v2 = 0.f, v3 = 0.f;
                {
                    const int ix = 2 * tx - 1 + kw;
                    if (vy && (unsigned)ix < 256u) v0 = row[ix];
                    if (vy && (unsigned)(ix +  64) < 256u) v1 = row[ix +  64];
                    if (vy && (unsigned)(ix + 128) < 256u) v2 = row[ix + 128];
                    if (vy && (unsigned)(ix + 192) < 256u) v3 = row[ix + 192];
                }
                const int tap = (ci * 5 + kh) * 5 + kw;
                const float4 wa = *(const float4*)&wl[tap * 8];
                const float4 wb = *(const float4*)&wl[tap * 8 + 4];
                acc[0][0]=fmaf(v0,wa.x,acc[0][0]); acc[0][1]=fmaf(v0,wa.y,acc[0][1]);
                acc[0][2]=fmaf(v0,wa.z,acc[0][2]); acc[0][3]=fmaf(v0,wa.w,acc[0][3]);
                acc[0][4]=fmaf(v0,wb.x,acc[0][4]); acc[0][5]=fmaf(v0,wb.y,acc[0][5]);
                acc[0][6]=fmaf(v0,wb.z,acc[0][6]); acc[0][7]=fmaf(v0,wb.w,acc[0][7]);
                acc[1][0]=fmaf(v1,wa.x,acc[1][0]); acc[1][1]=fmaf(v1,wa.y,acc[1][1]);
                acc[1][2]=fmaf(v1,wa.z,acc[1][2]); acc[1][3]=fmaf(v1,wa.w,acc[1][3]);
                acc[1][4]=fmaf(v1,wb.x,acc[1][4]); acc[1][5]=fmaf(v1,wb.y,acc[1][5]);
                acc[1][6]=fmaf(v1,wb.z,acc[1][6]); acc[1][7]=fmaf(v1,wb.w,acc[1][7]);
                acc[2][0]=fmaf(v2,wa.x,acc[2][0]); acc[2][1]=fmaf(v2,wa.y,acc[2][1]);
                acc[2][2]=fmaf(v2,wa.z,acc[2][2]); acc[2][3]=fmaf(v2,wa.w,acc[2][3]);
                acc[2][4]=fmaf(v2,wb.x,acc[2][4]); acc[2][5]=fmaf(v2,wb.y,acc[2][5]);
                acc[2][6]=fmaf(v2,wb.z,acc[2][6]); acc[2][7]=fmaf(v2,wb.w,acc[2][7]);
                acc[3][0]=fmaf(v3,wa.x,acc[3][0]); acc[3][1]=fmaf(v3,wa.y,acc[3][1]);
                acc[3][2]=fmaf(v3,wa.z,acc[3][2]); acc[3][3]=fmaf(v3,wa.w,acc[3][3]);
                acc[3][4]=fmaf(v3,wb.x,acc[3][4]); acc[3][5]=fmaf(v3,wb.y,acc[3][5]);
                acc[3][6]=fmaf(v3,wb.z,acc[3][6]); acc[3][7]=fmaf(v3,wb.w,acc[3][7]);
            }
        }
    }
    // zero invalid pixels (stats correctness), then store valid ones
    if (oy >= 127) {
        #pragma unroll
        for (int p = 0; p < 4; ++p)
            #pragma unroll
            for (int co = 0; co < 8; ++co) acc[p][co] = 0.f;
    }
    #pragma unroll
    for (int p = 0; p < 4; ++p)
        if (tx + 32 * p >= 127) {
            #pragma unroll
            for (int co = 0; co < 8; ++co) acc[p][co] = 0.f;
        }
    if (oy < 127) {
        #pragma unroll
        for (int p = 0; p < 4; ++p) {
            const int ox = tx + 32 * p;
            if (ox < 127) {
                #pragma unroll
                for (int co = 0; co < 8; ++co)
                    out[(((size_t)n * 8 + co) * 127 + oy) * 127 + ox] = acc[p][co];
            }
        }
    }
    float s[8], q[8];
    #pragma unroll
    for (int co = 0; co < 8; ++co) {
        s[co] = acc[0][co] + acc[1][co] + acc[2][co] + acc[3][co];
        q[co] = acc[0][co] * acc[0][co] + acc[1][co] * acc[1][co]
              + acc[2][co] * acc[2][co] + acc[3][co] * acc[3][co];
    }
    stats_write<8, 4>(s, q, psum, psq, n * 16 + bx, 1024, redbuf, tid);
}

// ---- encoder conv2: 8->16, 3x3 s2 p1, 127->64. PX=1, BN1+ReLU on load. -----
// grid (16,1,64) = 1024 blocks -> 4 waves/SIMD.
__global__ __launch_bounds__(256, 4)
void conv2_k(const float* __restrict__ in, const float* __restrict__ w,
             const float* __restrict__ ssin, float* __restrict__ out,
             float* __restrict__ psum, float* __restrict__ psq) {
    __shared__ float wl[1152];               // [tap][16co], tap=ci*9+kh*3+kw
    __shared__ float ssl[16];
    __shared__ float redbuf[4 * 2 * 16];
    const int tid = threadIdx.x;
    const int bx = blockIdx.x, n = blockIdx.z;
    for (int i = tid; i < 1152; i += 256) {
        const int co = i & 15, tap = i >> 4;
        wl[i] = w[co * 72 + tap];
    }
    if (tid < 16) ssl[tid] = ssin[tid];
    __syncthreads();

    const int p = bx * 256 + tid;            // 0..4095, all valid
    const int oy = p >> 6, ox = p & 63;
    const int iy0 = 2 * oy - 1, ix0 = 2 * ox - 1;
    const float* inb = in + (size_t)n * 8 * 127 * 127;

    float acc[16];
    #pragma unroll
    for (int co = 0; co < 16; ++co) acc[co] = 0.f;

    #pragma unroll 1
    for (int ci = 0; ci < 8; ++ci) {
        const float sc = ssl[2 * ci], sh = ssl[2 * ci + 1];
        const float* base = inb + ci * 127 * 127;
        #pragma unroll
        for (int kh = 0; kh < 3; ++kh) {
            const int iy = iy0 + kh;
            const bool vy = (unsigned)iy < 127u;
            #pragma unroll
            for (int kw = 0; kw < 3; ++kw) {
                const int ix = ix0 + kw;
                float v = 0.f;
                if (vy && (unsigned)ix < 127u)
                    v = fmaxf(base[iy * 127 + ix] * sc + sh, 0.f);
                const int tap = ci * 9 + kh * 3 + kw;
                const float4 wa = *(const float4*)&wl[tap * 16];
                const float4 wb = *(const float4*)&wl[tap * 16 + 4];
                const float4 wc = *(const float4*)&wl[tap * 16 + 8];
                const float4 wd = *(const float4*)&wl[tap * 16 + 12];
                acc[ 0]=fmaf(v,wa.x,acc[ 0]); acc[ 1]=fmaf(v,wa.y,acc[ 1]);
                acc[ 2]=fmaf(v,wa.z,acc[ 2]); acc[ 3]=fmaf(v,wa.w,acc[ 3]);
                acc[ 4]=fmaf(v,wb.x,acc[ 4]); acc[ 5]=fmaf(v,wb.y,acc[ 5]);
                acc[ 6]=fmaf(v,wb.z,acc[ 6]); acc[ 7]=fmaf(v,wb.w,acc[ 7]);
                acc[ 8]=fmaf(v,wc.x,acc[ 8]); acc[ 9]=fmaf(v,wc.y,acc[ 9]);
                acc[10]=fmaf(v,wc.z,acc[10]); acc[11]=fmaf(v,wc.w,acc[11]);
                acc[12]=fmaf(v,wd.x,acc[12]); acc[13]=fmaf(v,wd.y,acc[13]);
                acc[14]=fmaf(v,wd.z,acc[14]); acc[15]=fmaf(v,wd.w,acc[15]);
            }
        }
    }
    #pragma unroll
    for (int co = 0; co < 16; ++co)
        out[(((size_t)n * 16 + co) * 64 + oy) * 64 + ox] = acc[co];
    float s[16], q[16];
    #pragma unroll
    for (int co = 0; co < 16; ++co) { s[co] = acc[co]; q[co] = acc[co] * acc[co]; }
    stats_write<16, 4>(s, q, psum, psq, n * 16 + bx, 1024, redbuf, tid);
}

// ---- encoder conv3: 16->4, 3x3 s2 p1, 64->32. BN2+ReLU on load. ------------
__global__ __launch_bounds__(256, 4)
void conv3_k(const float* __restrict__ in, const float* __restrict__ w,
             const float* __restrict__ ssin, float* __restrict__ out,
             float* __restrict__ psum, float* __restrict__ psq) {
    __shared__ float wl[576];                // [tap][4co], tap=ci*9+kh*3+kw
    __shared__ float ssl[32];
    __shared__ float redbuf[4 * 2 * 4];
    const int tid = threadIdx.x;
    const int bx = blockIdx.x, n = blockIdx.z;
    for (int i = tid; i < 576; i += 256) {
        const int co = i & 3, tap = i >> 2;
        wl[i] = w[co * 144 + tap];
    }
    if (tid < 32) ssl[tid] = ssin[tid];
    __syncthreads();

    const int p = bx * 256 + tid;            // 0..1023 exact
    const int oy = p >> 5, ox = p & 31;
    const int iy0 = 2 * oy - 1, ix0 = 2 * ox - 1;
    const float* inb = in + (size_t)n * 16 * 64 * 64;
    float acc[4] = {0.f, 0.f, 0.f, 0.f};

    #pragma unroll 1
    for (int ci = 0; ci < 16; ++ci) {
        const float sc = ssl[2 * ci], sh = ssl[2 * ci + 1];
        const float* base = inb + ci * 64 * 64;
        #pragma unroll
        for (int kh = 0; kh < 3; ++kh) {
            const int iy = iy0 + kh;
            const bool vy = (unsigned)iy < 64u;
            #pragma unroll
            for (int kw = 0; kw < 3; ++kw) {
                const int ix = ix0 + kw;
                float v = 0.f;
                if (vy && (unsigned)ix < 64u)
                    v = fmaxf(base[iy * 64 + ix] * sc + sh, 0.f);
                const float4 wa = *(const float4*)&wl[(ci * 9 + kh * 3 + kw) * 4];
                acc[0]=fmaf(v,wa.x,acc[0]); acc[1]=fmaf(v,wa.y,acc[1]);
                acc[2]=fmaf(v,wa.z,acc[2]); acc[3]=fmaf(v,wa.w,acc[3]);
            }
        }
    }
    #pragma unroll
    for (int co = 0; co < 4; ++co)
        out[((size_t)n * 4 + co) * 1024 + p] = acc[co];
    float s[4], q[4];
    #pragma unroll
    for (int co = 0; co < 4; ++co) { s[co] = acc[co]; q[co] = acc[co] * acc[co]; }
    stats_write<4, 4>(s, q, psum, psq, n * 4 + bx, 256, redbuf, tid);
}

// ---- VQ with fused BN3+ReLU of latents; float4 codebook reads --------------
__global__ __launch_bounds__(256, 4)
void vq_k(const float* __restrict__ raw, const float* __restrict__ ss,
          const float* __restrict__ emb, float* __restrict__ out_lat,
          float* __restrict__ out_q, float* __restrict__ lossp) {
    __shared__ float4 e4[512];
    __shared__ float ee[512];
    __shared__ float ssl[8];
    __shared__ float redbuf[4];
    for (int i = threadIdx.x; i < 512; i += 256) {
        const float4 t = ((const float4*)emb)[i];
        e4[i] = t;
        ee[i] = t.x * t.x + t.y * t.y + t.z * t.z + t.w * t.w;
    }
    if (threadIdx.x < 8) ssl[threadIdx.x] = ss[threadIdx.x];
    __syncthreads();

    const int t = blockIdx.x * 256 + threadIdx.x;
    const int b = t >> 10, p = t & 1023;
    const float* rb = raw + ((size_t)b * 4) * 1024 + p;
    const float z0 = fmaxf(rb[0]    * ssl[0] + ssl[1], 0.f);
    const float z1 = fmaxf(rb[1024] * ssl[2] + ssl[3], 0.f);
    const float z2 = fmaxf(rb[2048] * ssl[4] + ssl[5], 0.f);
    const float z3 = fmaxf(rb[3072] * ssl[6] + ssl[7], 0.f);
    float* lb = out_lat + ((size_t)b * 4) * 1024 + p;
    lb[0] = z0; lb[1024] = z1; lb[2048] = z2; lb[3072] = z3;

    const float zz = z0 * z0 + z1 * z1 + z2 * z2 + z3 * z3;
    int best = 0;
    float bd = INFINITY;
    #pragma unroll 4
    for (int k = 0; k < 512; ++k) {
        const float4 ek = e4[k];
        const float dot = z0 * ek.x + z1 * ek.y + z2 * ek.z + z3 * ek.w;
        const float d = zz - 2.f * dot + ee[k];   // expanded form, as reference
        if (d < bd) { bd = d; best = k; }         // strict < = first-occurrence argmin
    }
    const float4 qv = e4[best];
    float* qb = out_q + ((size_t)b * 4) * 1024 + p;
    qb[0] = qv.x; qb[1024] = qv.y; qb[2048] = qv.z; qb[3072] = qv.w;

    float ssd = (qv.x - z0) * (qv.x - z0) + (qv.y - z1) * (qv.y - z1)
              + (qv.z - z2) * (qv.z - z2) + (qv.w - z3) * (qv.w - z3);
    #pragma unroll
    for (int o = 32; o > 0; o >>= 1) ssd += __shfl_down(ssd, o, 64);
    const int lane = threadIdx.x & 63, wid = threadIdx.x >> 6;
    if (lane == 0) redbuf[wid] = ssd;
    __syncthreads();
    if (threadIdx.x == 0)
        lossp[blockIdx.x] = redbuf[0] + redbuf[1] + redbuf[2] + redbuf[3];
}

__global__ __launch_bounds__(256)
void loss_final_k(const float* __restrict__ partial, float* __restrict__ out_cb,
                  float* __restrict__ out_cm) {
    __shared__ float redbuf[4];
    float s = partial[threadIdx.x];
    #pragma unroll
    for (int o = 32; o > 0; o >>= 1) s += __shfl_down(s, o, 64);
    const int lane = threadIdx.x & 63, wid = threadIdx.x >> 6;
    if (lane == 0) redbuf[wid] = s;
    __syncthreads();
    if (threadIdx.x == 0) {
        const float L = (redbuf[0] + redbuf[1] + redbuf[2] + redbuf[3]) * (1.f / 262144.f);
        *out_cb = L;
        *out_cm = L;
    }
}

// ---- decoder convT1: 4->16, 3x3 s2 p0, 32->65. Parity rows, col pairs. -----
__global__ __launch_bounds__(256, 4)
void dect1_k(const float* __restrict__ in, const float* __restrict__ w,
             float* __restrict__ out, float* __restrict__ psum,
             float* __restrict__ psq) {
    __shared__ float wl[576];                // [tap][16co], tap=ci*9+kh*3+kw
    __shared__ float redbuf[4 * 2 * 16];
    const int tid = threadIdx.x;
    const int cy = blockIdx.y, n = blockIdx.z;
    for (int i = tid; i < 576; i += 256) {
        const int co = i & 15, tap = i >> 4;
        const int ci = tap / 9, k = tap % 9;
        wl[i] = w[(ci * 16 + co) * 9 + k];
    }
    __syncthreads();

    const int Ry = 33 - cy;                  // rows in this parity class
    const int p = blockIdx.x * 256 + tid;
    const bool active = p < Ry * 33;
    const int ry = p / 33, rx = p % 33;
    const int oy = 2 * ry + cy;
    float acc_e[16], acc_o[16];
    #pragma unroll
    for (int co = 0; co < 16; ++co) { acc_e[co] = 0.f; acc_o[co] = 0.f; }

    if (active) {
        const float* inb = in + (size_t)n * 4 * 1024;
        #pragma unroll 1
        for (int ci = 0; ci < 4; ++ci) {
            #pragma unroll 1
            for (int kk = 0; kk < 2; ++kk) {
                int kh, iy; bool vy;
                if (cy == 0) { kh = kk * 2; iy = ry - (kk ? 1 : 0); vy = kk ? (ry >= 1) : (ry < 32); }
                else         { if (kk) break; kh = 1; iy = ry; vy = true; }
                const float* r = inb + (ci * 32 + iy) * 32;
                const float vL = (vy && rx >= 1) ? r[rx - 1] : 0.f;   // kw=2 src
                const float vR = (vy && rx < 32) ? r[rx]     : 0.f;   // kw=0/1 src
                const int t0 = (ci * 9 + kh * 3) * 16;
                const float4 a0 = *(const float4*)&wl[t0];        // kw0 co0-3
                const float4 a1 = *(const float4*)&wl[t0 + 4];
                const float4 a2 = *(const float4*)&wl[t0 + 8];
                const float4 a3 = *(const float4*)&wl[t0 + 12];
                const float4 b0 = *(const float4*)&wl[t0 + 16];   // kw1
                const float4 b1 = *(const float4*)&wl[t0 + 20];
                const float4 b2 = *(const float4*)&wl[t0 + 24];
                const float4 b3 = *(const float4*)&wl[t0 + 28];
                const float4 c0 = *(const float4*)&wl[t0 + 32];   // kw2
                const float4 c1 = *(const float4*)&wl[t0 + 36];
                const float4 c2 = *(const float4*)&wl[t0 + 40];
                const float4 c3 = *(const float4*)&wl[t0 + 44];
                acc_e[ 0]=fmaf(vR,a0.x,fmaf(vL,c0.x,acc_e[ 0])); acc_e[ 1]=fmaf(vR,a0.y,fmaf(vL,c0.y,acc_e[ 1]));
                acc_e[ 2]=fmaf(vR,a0.z,fmaf(vL,c0.z,acc_e[ 2])); acc_e[ 3]=fmaf(vR,a0.w,fmaf(vL,c0.w,acc_e[ 3]));
                acc_e[ 4]=fmaf(vR,a1.x,fmaf(vL,c1.x,acc_e[ 4])); acc_e[ 5]=fmaf(vR,a1.y,fmaf(vL,c1.y,acc_e[ 5]));
                acc_e[ 6]=fmaf(vR,a1.z,fmaf(vL,c1.z,acc_e[ 6])); acc_e[ 7]=fmaf(vR,a1.w,fmaf(vL,c1.w,acc_e[ 7]));
                acc_e[ 8]=fmaf(vR,a2.x,fmaf(vL,c2.x,acc_e[ 8])); acc_e[ 9]=fmaf(vR,a2.y,fmaf(vL,c2.y,acc_e[ 9]));
                acc_e[10]=fmaf(vR,a2.z,fmaf(vL,c2.z,acc_e[10])); acc_e[11]=fmaf(vR,a2.w,fmaf(vL,c2.w,acc_e[11]));
                acc_e[12]=fmaf(vR,a3.x,fmaf(vL,c3.x,acc_e[12])); acc_e[13]=fmaf(vR,a3.y,fmaf(vL,c3.y,acc_e[13]));
                acc_e[14]=fmaf(vR,a3.z,fmaf(vL,c3.z,acc_e[14])); acc_e[15]=fmaf(vR,a3.w,fmaf(vL,c3.w,acc_e[15]));
                acc_o[ 0]=fmaf(vR,b0.x,acc_o[ 0]); acc_o[ 1]=fmaf(vR,b0.y,acc_o[ 1]);
                acc_o[ 2]=fmaf(vR,b0.z,acc_o[ 2]); acc_o[ 3]=fmaf(vR,b0.w,acc_o[ 3]);
                acc_o[ 4]=fmaf(vR,b1.x,acc_o[ 4]); acc_o[ 5]=fmaf(vR,b1.y,acc_o[ 5]);
                acc_o[ 6]=fmaf(vR,b1.z,acc_o[ 6]); acc_o[ 7]=fmaf(vR,b1.w,acc_o[ 7]);
                acc_o[ 8]=fmaf(vR,b2.x,acc_o[ 8]); acc_o[ 9]=fmaf(vR,b2.y,acc_o[ 9]);
                acc_o[10]=fmaf(vR,b2.z,acc_o[10]); acc_o[11]=fmaf(vR,b2.w,acc_o[11]);
                acc_o[12]=fmaf(vR,b3.x,acc_o[12]); acc_o[13]=fmaf(vR,b3.y,acc_o[13]);
                acc_o[14]=fmaf(vR,b3.z,acc_o[14]); acc_o[15]=fmaf(vR,b3.w,acc_o[15]);
            }
        }
        #pragma unroll
        for (int co = 0; co < 16; ++co) {
            float* o = out + (((size_t)n * 16 + co) * 65 + oy) * 65 + 2 * rx;
            o[0] = acc_e[co];
            if (rx < 32) o[1] = acc_o[co];
        }
    }
    float s[16], q[16];
    #pragma unroll
    for (int co = 0; co < 16; ++co) {        // acc_o auto-0 at rx==32 (vR masked)
        s[co] = acc_e[co] + acc_o[co];
        q[co] = acc_e[co] * acc_e[co] + acc_o[co] * acc_o[co];
    }
    stats_write<16, 4>(s, q, psum, psq, (n * 2 + cy) * 5 + blockIdx.x, 640, redbuf, tid);
}

// ---- decoder convT2: 16->8, 3x3 s2 p1, 65->129. BN(dec1)+ReLU on load. -----
__global__ __launch_bounds__(256, 4)
void dect2_k(const float* __restrict__ in, const float* __restrict__ w,
             const float* __restrict__ ssin, float* __restrict__ out,
             float* __restrict__ psum, float* __restrict__ psq) {
    __shared__ float wl[1152];               // [tap][8co], tap=ci*9+kh*3+kw
    __shared__ float ssl[32];
    __shared__ float redbuf[4 * 2 * 8];
    const int tid = threadIdx.x;
    const int cy = blockIdx.y, n = blockIdx.z;
    for (int i = tid; i < 1152; i += 256) {
        const int co = i & 7, tap = i >> 3;
        const int ci = tap / 9, k = tap % 9;
        wl[i] = w[(ci * 8 + co) * 9 + k];
    }
    if (tid < 32) ssl[tid] = ssin[tid];
    __syncthreads();

    const int Ry = 65 - cy;
    const int p = blockIdx.x * 256 + tid;
    const bool active = p < Ry * 65;
    const int ry = p / 65, rx = p % 65;
    const int oy = 2 * ry + cy;
    float acc_e[8], acc_o[8];
    #pragma unroll
    for (int co = 0; co < 8; ++co) { acc_e[co] = 0.f; acc_o[co] = 0.f; }

    if (active) {
        const float* inb = in + (size_t)n * 16 * 65 * 65;
        #pragma unroll 1
        for (int ci = 0; ci < 16; ++ci) {
            const float sc = ssl[2 * ci], sh = ssl[2 * ci + 1];
            #pragma unroll 1
            for (int kk = 0; kk < 2; ++kk) {
                int kh, iy;
                if (cy == 0) { if (kk) break; kh = 1; iy = ry; }   // oy even: kh=1 only
                else         { kh = kk * 2; iy = kk ? ry : ry + 1; } // oy odd: kh=0(iy=ry+1), kh=2(iy=ry)
                const float* r = inb + (ci * 65 + iy) * 65;
                const float vR = fmaxf(r[rx] * sc + sh, 0.f);
                float vP = 0.f;
                if (rx < 64) vP = fmaxf(r[rx + 1] * sc + sh, 0.f);
                const int t0 = (ci * 9 + kh * 3) * 8;
                const float4 a0 = *(const float4*)&wl[t0];        // kw0
                const float4 a1 = *(const float4*)&wl[t0 + 4];
                const float4 b0 = *(const float4*)&wl[t0 + 8];    // kw1
                const float4 b1 = *(const float4*)&wl[t0 + 12];
                const float4 c0 = *(const float4*)&wl[t0 + 16];   // kw2
                const float4 c1 = *(const float4*)&wl[t0 + 20];
                acc_e[0]=fmaf(vR,b0.x,acc_e[0]); acc_e[1]=fmaf(vR,b0.y,acc_e[1]);
                acc_e[2]=fmaf(vR,b0.z,acc_e[2]); acc_e[3]=fmaf(vR,b0.w,acc_e[3]);
                acc_e[4]=fmaf(vR,b1.x,acc_e[4]); acc_e[5]=fmaf(vR,b1.y,acc_e[5]);
                acc_e[6]=fmaf(vR,b1.z,acc_e[6]); acc_e[7]=fmaf(vR,b1.w,acc_e[7]);
                acc_o[0]=fmaf(vP,a0.x,fmaf(vR,c0.x,acc_o[0])); acc_o[1]=fmaf(vP,a0.y,fmaf(vR,c0.y,acc_o[1]));
                acc_o[2]=fmaf(vP,a0.z,fmaf(vR,c0.z,acc_o[2])); acc_o[3]=fmaf(vP,a0.w,fmaf(vR,c0.w,acc_o[3]));
                acc_o[4]=fmaf(vP,a1.x,fmaf(vR,c1.x,acc_o[4])); acc_o[5]=fmaf(vP,a1.y,fmaf(vR,c1.y,acc_o[5]));
                acc_o[6]=fmaf(vP,a1.z,fmaf(vR,c1.z,acc_o[6])); acc_o[7]=fmaf(vP,a1.w,fmaf(vR,c1.w,acc_o[7]));
            }
        }
        if (rx >= 64) {                      // odd col 129 doesn't exist
            #pragma unroll
            for (int co = 0; co < 8; ++co) acc_o[co] = 0.f;
        }
        #pragma unroll
        for (int co = 0; co < 8; ++co) {
            float* o = out + (((size_t)n * 8 + co) * 129 + oy) * 129 + 2 * rx;
            o[0] = acc_e[co];
            if (rx < 64) o[1] = acc_o[co];
        }
    }
    float s[8], q[8];
    #pragma unroll
    for (int co = 0; co < 8; ++co) {
        s[co] = acc_e[co] + acc_o[co];
        q[co] = acc_e[co] * acc_e[co] + acc_o[co] * acc_o[co];
    }
    stats_write<8, 4>(s, q, psum, psq, (n * 2 + cy) * 17 + blockIdx.x, 2176, redbuf, tid);
}

// ---- decoder convT3: 8->3, 2x2 s2 p1, 129->256. 2x2 quad per thread. -------
__global__ __launch_bounds__(256, 4)
void dec3_k(const float* __restrict__ in, const float* __restrict__ w,
            const float* __restrict__ ssin, const float* __restrict__ bias,
            float* __restrict__ out) {
    __shared__ float wl[96];                 // (ci*3+co)*4 + kh*2+kw
    __shared__ float ssl[16];
    __shared__ float bl[3];
    const int tid = threadIdx.x;
    if (tid < 96) wl[tid] = w[tid];
    if (tid < 16) ssl[tid] = ssin[tid];
    if (tid < 3)  bl[tid] = bias[tid];
    __syncthreads();

    const int n = blockIdx.z;
    const int p = blockIdx.x * 256 + tid;    // 0..16383 exact (128x128 quads)
    const int ry = p >> 7, rx = p & 127;
    const float* inb = in + (size_t)n * 8 * 129 * 129;

    float acc[2][2][3];
    #pragma unroll
    for (int dy = 0; dy < 2; ++dy)
        #pragma unroll
        for (int dx = 0; dx < 2; ++dx)
            #pragma unroll
            for (int co = 0; co < 3; ++co) acc[dy][dx][co] = bl[co];

    #pragma unroll 1
    for (int ci = 0; ci < 8; ++ci) {
        const float sc = ssl[2 * ci], sh = ssl[2 * ci + 1];
        const float* base = inb + (ci * 129 + ry) * 129 + rx;
        const float v00 = fmaxf(base[0]   * sc + sh, 0.f);
        const float v01 = fmaxf(base[1]   * sc + sh, 0.f);
        const float v10 = fmaxf(base[129] * sc + sh, 0.f);
        const float v11 = fmaxf(base[130] * sc + sh, 0.f);
        #pragma unroll
        for (int co = 0; co < 3; ++co) {
            const int b = (ci * 3 + co) * 4;
            acc[0][0][co] = fmaf(v00, wl[b + 3], acc[0][0][co]);   // kh=1,kw=1
            acc[0][1][co] = fmaf(v01, wl[b + 2], acc[0][1][co]);   // kh=1,kw=0
            acc[1][0][co] = fmaf(v10, wl[b + 1], acc[1][0][co]);   // kh=0,kw=1
            acc[1][1][co] = fmaf(v11, wl[b + 0], acc[1][1][co]);   // kh=0,kw=0
        }
    }
    #pragma unroll
    for (int co = 0; co < 3; ++co) {
        #pragma unroll
        for (int dy = 0; dy < 2; ++dy) {
            float a0 = 1.f / (1.f + __expf(-acc[dy][0][co]));
            float a1 = 1.f / (1.f + __expf(-acc[dy][1][co]));
            float2 v2 = make_float2(a0, a1);
            float* o = out + (((size_t)n * 3 + co) << 16) + (size_t)(2 * ry + dy) * 256 + 2 * rx;
            *reinterpret_cast<float2*>(o) = v2;   // offset even -> 8B aligned
        }
    }
}

// ---------------------------------------------------------------------------
extern "C" void kernel_launch(void* const* d_in, const int* in_sizes, int n_in,
                              void* d_out, int out_size, void* d_ws, size_t ws_size,
                              hipStream_t stream) {
    const float* x      = (const float*)d_in[0];
    const float* ew1    = (const float*)d_in[1];
    const float* eg1    = (const float*)d_in[2];
    const float* eb1    = (const float*)d_in[3];
    const float* ew2    = (const float*)d_in[4];
    const float* eg2    = (const float*)d_in[5];
    const float* eb2    = (const float*)d_in[6];
    const float* ew3    = (const float*)d_in[7];
    const float* eg3    = (const float*)d_in[8];
    const float* eb3    = (const float*)d_in[9];
    const float* emb    = (const float*)d_in[10];
    const float* dw1    = (const float*)d_in[11];
    const float* dg1    = (const float*)d_in[12];
    const float* db1    = (const float*)d_in[13];
    const float* dw2    = (const float*)d_in[14];
    const float* dg2    = (const float*)d_in[15];
    const float* db2    = (const float*)d_in[16];
    const float* dw3    = (const float*)d_in[17];
    const float* dbias3 = (const float*)d_in[18];

    float* out_lat = (float*)d_out;
    float* out_q   = out_lat + 262144;
    float* out_dec = out_q + 262144;
    float* out_cb  = (float*)d_out + 13107200;
    float* out_cm  = out_cb + 1;

    float* bufA  = (float*)d_ws;          // h1 raw (8258048) then g2 raw (8520768)
    float* bufB  = bufA + 8520768;        // h2 raw (4194304) then g1 raw (4326400)
    float* bufC  = bufB + 4326400;        // conv3 raw, 262144
    float* psum  = bufC + 262144;
    float* psq   = psum + 18432;
    float* ssb   = psq + 18432;
    float* lossp = ssb + 32;

    // encoder 1
    conv1_k<<<dim3(16, 1, 64), 256, 0, stream>>>(x, ew1, bufA, psum, psq);
    red_final_k<8><<<8, 64, 0, stream>>>(psum, psq, eg1, eb1, ssb,
                                         1.f / (64.f * 16129.f), 1024);
    // encoder 2 (BN1+ReLU fused on load)
    conv2_k<<<dim3(16, 1, 64), 256, 0, stream>>>(bufA, ew2, ssb, bufB, psum, psq);
    red_final_k<16><<<16, 64, 0, stream>>>(psum, psq, eg2, eb2, ssb,
                                           1.f / (64.f * 4096.f), 1024);
    // encoder 3 (BN2+ReLU fused on load)
    conv3_k<<<dim3(4, 1, 64), 256, 0, stream>>>(bufB, ew3, ssb, bufC, psum, psq);
    red_final_k<4><<<4, 64, 0, stream>>>(psum, psq, eg3, eb3, ssb,
                                         1.f / (64.f * 1024.f), 256);
    // VQ (+ BN3+ReLU fused, latents written here) + losses
    vq_k<<<256, 256, 0, stream>>>(bufC, ssb, emb, out_lat, out_q, lossp);
    loss_final_k<<<1, 256, 0, stream>>>(lossp, out_cb, out_cm);
    // decoder 1: parity convT
    dect1_k<<<dim3(5, 2, 64), 256, 0, stream>>>(out_q, dw1, bufB, psum, psq);
    red_final_k<16><<<16, 64, 0, stream>>>(psum, psq, dg1, db1, ssb,
                                           1.f / (64.f * 4225.f), 640);
    // decoder 2: parity convT, BN(dec1)+ReLU fused
    dect2_k<<<dim3(17, 2, 64), 256, 0, stream>>>(bufB, dw2, ssb, bufA, psum, psq);
    red_final_k<8><<<8, 64, 0, stream>>>(psum, psq, dg2, db2, ssb,
                                         1.f / (64.f * 16641.f), 2176);
    // decoder 3: quad, BN(dec2)+ReLU fused, bias+sigmoid
    dec3_k<<<dim3(64, 1, 64), 256, 0, stream>>>(bufA, dw3, ssb, dbias3, out_dec);
}